// Round 1
// baseline (318.960 us; speedup 1.0000x reference)
//
#include <hip/hip_runtime.h>
#include <hip/hip_bf16.h>

#define NN 16384
#define EE 524288
#define DDIM 128
#define HDIM 256
#define CDIM 10
#define GG 64
#define MAXD 128
#define WPR 512   // bitmap words per row = NN/32

// workspace byte offsets (aliased; kernels are sequential on one stream)
#define OFF_BM   0ull          // 32 MB bitmap, dead after extract
#define OFF_Y1   0ull          // 8 MB   (alias BM)
#define OFF_H1   8388608ull    // 16 MB  (alias BM)
#define OFF_Y2   25165824ull   // 16 MB  (tail aliases BM, rest fresh)
#define OFF_ELL  41943040ull   // 8 MB
#define OFF_DIS  50331648ull   // 64 KB
#define OFF_DEG  50397184ull   // 64 KB
#define OFF_H2   0ull          // 16 MB  (alias Y1/H1, both dead by then)
#define OFF_POOL 50462720ull   // 64 KB
#define OFF_CNT  50528256ull   // 256 B

__global__ void zero_u4(uint4* p, int n16) {
    int i = blockIdx.x * blockDim.x + threadIdx.x;
    int stride = gridDim.x * blockDim.x;
    uint4 z = make_uint4(0u, 0u, 0u, 0u);
    for (; i < n16; i += stride) p[i] = z;
}

__global__ void zero_f(float* p, int n) {
    int i = blockIdx.x * blockDim.x + threadIdx.x;
    if (i < n) p[i] = 0.0f;
}

__global__ void selfloop_kernel(unsigned* bm) {
    int i = blockIdx.x * blockDim.x + threadIdx.x;
    if (i < NN) atomicOr(&bm[i * WPR + (i >> 5)], 1u << (i & 31));
}

__global__ void edge_kernel(const int* __restrict__ ei, unsigned* bm) {
    int e = blockIdx.x * blockDim.x + threadIdx.x;
    if (e < EE) {
        int s = ei[e];
        int d = ei[EE + e];
        atomicOr(&bm[s * WPR + (d >> 5)], 1u << (d & 31));
    }
}

// one wave per row: popcount + prefix scan -> ELL cols (sorted), deg, dis
__global__ void extract_kernel(const unsigned* __restrict__ bm,
                               int* __restrict__ ell, int* __restrict__ deg,
                               float* __restrict__ dis) {
    int gtid = blockIdx.x * blockDim.x + threadIdx.x;
    int row  = gtid >> 6;
    int lane = threadIdx.x & 63;
    if (row >= NN) return;
    const uint4* wp = (const uint4*)(bm + (size_t)row * WPR + lane * 8);
    uint4 a = wp[0];
    uint4 b = wp[1];
    unsigned w[8] = {a.x, a.y, a.z, a.w, b.x, b.y, b.z, b.w};
    int pc = 0;
#pragma unroll
    for (int k = 0; k < 8; k++) pc += __popc(w[k]);
    // inclusive scan
    int pre = pc;
#pragma unroll
    for (int off = 1; off < 64; off <<= 1) {
        int o = __shfl_up(pre, off, 64);
        if (lane >= off) pre += o;
    }
    int total = __shfl(pre, 63, 64);
    pre -= pc;  // exclusive
    int base = row * MAXD;
    int pos = pre;
#pragma unroll
    for (int k = 0; k < 8; k++) {
        unsigned bits = w[k];
        int cbase = lane * 256 + k * 32;
        while (bits) {
            int bit = __ffs(bits) - 1;
            if (pos < MAXD) ell[base + pos] = cbase + bit;
            pos++;
            bits &= bits - 1;
        }
    }
    if (lane == 0) {
        deg[row] = total < MAXD ? total : MAXD;
        dis[row] = 1.0f / sqrtf((float)total);
    }
}

// y[row,:] = dis[row] * sum_k dis[c_k] * x[c_k,:]
template <int DC>
__global__ void spmm_kernel(const float* __restrict__ x,
                            const int* __restrict__ ell,
                            const int* __restrict__ deg,
                            const float* __restrict__ dis,
                            float* __restrict__ y) {
    __shared__ int   sc[MAXD];
    __shared__ float sw[MAXD];
    int row = blockIdx.x;
    int t = threadIdx.x;
    int d = deg[row];
    if (t < d) {
        int c = ell[row * MAXD + t];
        sc[t] = c;
        sw[t] = dis[c];
    }
    __syncthreads();
    float acc = 0.0f;
    for (int k = 0; k < d; k++) acc = fmaf(sw[k], x[sc[k] * DC + t], acc);
    y[row * DC + t] = dis[row] * acc;
}

// H = relu(Y @ W + b); Y:[M,K], W:[K,256], tile 256 rows x 16 cols per block
template <int K>
__global__ __launch_bounds__(256) void gemm_relu_kernel(
        const float* __restrict__ Y, const float* __restrict__ W,
        const float* __restrict__ b, float* __restrict__ H) {
    __shared__ float ys[256][33];
    int r0 = blockIdx.x * 256;
    int j0 = blockIdx.y * 16;
    int tid = threadIdx.x;
    float acc[16];
#pragma unroll
    for (int jj = 0; jj < 16; jj++) acc[jj] = 0.0f;

    for (int d0 = 0; d0 < K; d0 += 32) {
        __syncthreads();
#pragma unroll
        for (int c = 0; c < 32; c++) {
            int idx = c * 256 + tid;
            int r = idx >> 5;
            int d = idx & 31;
            ys[r][d] = Y[(r0 + r) * K + d0 + d];
        }
        __syncthreads();
        for (int d = 0; d < 32; d++) {
            float yv = ys[tid][d];
            const float* wrow = W + (d0 + d) * 256 + j0;
#pragma unroll
            for (int jj = 0; jj < 16; jj++) acc[jj] = fmaf(yv, wrow[jj], acc[jj]);
        }
    }
#pragma unroll
    for (int jj = 0; jj < 16; jj++) {
        float v = acc[jj] + b[j0 + jj];
        v = fmaxf(v, 0.0f);
        H[(r0 + tid) * 256 + j0 + jj] = v;
    }
}

// counts per graph (batch sorted, but histogram works regardless)
__global__ void count_kernel(const int* __restrict__ batch, float* cnt) {
    __shared__ int h[GG];
    int t = threadIdx.x;
    if (t < GG) h[t] = 0;
    __syncthreads();
    int i = blockIdx.x * blockDim.x + t;
    if (i < NN) atomicAdd(&h[batch[i]], 1);
    __syncthreads();
    if (t < GG && h[t] > 0) atomicAdd(&cnt[t], (float)h[t]);
}

// segment-sum 64 nodes per block (batch sorted -> run-length accumulate)
__global__ void pool_kernel(const float* __restrict__ h2,
                            const int* __restrict__ batch,
                            float* __restrict__ pooled) {
    int b = blockIdx.x;
    int t = threadIdx.x;  // feature dim, 256
    int n0 = b * 64;
    int cur = batch[n0];
    float acc = 0.0f;
    for (int n = 0; n < 64; n++) {
        int node = n0 + n;
        int g = batch[node];
        if (g != cur) {
            atomicAdd(&pooled[cur * 256 + t], acc);
            acc = 0.0f;
            cur = g;
        }
        acc += h2[node * 256 + t];
    }
    atomicAdd(&pooled[cur * 256 + t], acc);
}

// out[g,c] = (pooled[g,:]/cnt[g]) . Wc[:,c] + bc[c]
__global__ void head_kernel(const float* __restrict__ pooled,
                            const float* __restrict__ cnt,
                            const float* __restrict__ Wc,
                            const float* __restrict__ bc,
                            float* __restrict__ out) {
    int g = blockIdx.x;
    int l = threadIdx.x;  // 64
    float inv = 1.0f / fmaxf(cnt[g], 1.0f);
    float acc[CDIM];
#pragma unroll
    for (int c = 0; c < CDIM; c++) acc[c] = 0.0f;
    for (int t = l; t < 256; t += 64) {
        float pv = pooled[g * 256 + t] * inv;
#pragma unroll
        for (int c = 0; c < CDIM; c++) acc[c] = fmaf(pv, Wc[t * CDIM + c], acc[c]);
    }
#pragma unroll
    for (int c = 0; c < CDIM; c++) {
        float v = acc[c];
        for (int off = 32; off > 0; off >>= 1) v += __shfl_down(v, off, 64);
        if (l == 0) out[g * CDIM + c] = v + bc[c];
    }
}

extern "C" void kernel_launch(void* const* d_in, const int* in_sizes, int n_in,
                              void* d_out, int out_size, void* d_ws, size_t ws_size,
                              hipStream_t stream) {
    const float* x  = (const float*)d_in[0];
    const int*   ei = (const int*)d_in[1];
    const int*   batch = (const int*)d_in[2];
    const float* W1 = (const float*)d_in[3];
    const float* b1 = (const float*)d_in[4];
    const float* W2 = (const float*)d_in[5];
    const float* b2 = (const float*)d_in[6];
    const float* Wc = (const float*)d_in[7];
    const float* bc = (const float*)d_in[8];
    float* out = (float*)d_out;

    char* ws = (char*)d_ws;
    unsigned* bm  = (unsigned*)(ws + OFF_BM);
    float* y1     = (float*)(ws + OFF_Y1);
    float* h1     = (float*)(ws + OFF_H1);
    float* y2     = (float*)(ws + OFF_Y2);
    int*   ell    = (int*)(ws + OFF_ELL);
    float* dis    = (float*)(ws + OFF_DIS);
    int*   deg    = (int*)(ws + OFF_DEG);
    float* h2     = (float*)(ws + OFF_H2);
    float* pooled = (float*)(ws + OFF_POOL);
    float* cnt    = (float*)(ws + OFF_CNT);

    // 1) zero 32MB bitmap
    zero_u4<<<2048, 256, 0, stream>>>((uint4*)bm, (NN * WPR * 4) / 16);
    // 2) self loops + edges
    selfloop_kernel<<<NN / 256, 256, 0, stream>>>(bm);
    edge_kernel<<<EE / 256, 256, 0, stream>>>(ei, bm);
    // 3) bitmap -> ELL + deg + dis (wave per row)
    extract_kernel<<<(NN * 64) / 256, 256, 0, stream>>>(bm, ell, deg, dis);
    // 4) SpMM1: y1 = Ahat @ x   [N,128]
    spmm_kernel<DDIM><<<NN, DDIM, 0, stream>>>(x, ell, deg, dis, y1);
    // 5) GEMM1: h1 = relu(y1 @ W1 + b1)  [N,256]
    {
        dim3 grid(NN / 256, 256 / 16);
        gemm_relu_kernel<DDIM><<<grid, 256, 0, stream>>>(y1, W1, b1, h1);
    }
    // 6) SpMM2: y2 = Ahat @ h1  [N,256]
    spmm_kernel<HDIM><<<NN, HDIM, 0, stream>>>(h1, ell, deg, dis, y2);
    // 7) GEMM2: h2 = relu(y2 @ W2 + b2) [N,256]
    {
        dim3 grid(NN / 256, 256 / 16);
        gemm_relu_kernel<HDIM><<<grid, 256, 0, stream>>>(y2, W2, b2, h2);
    }
    // 8) pooled mean
    zero_f<<<(GG * 256 + GG + 255) / 256, 256, 0, stream>>>(pooled, GG * 256 + GG);
    count_kernel<<<NN / 256, 256, 0, stream>>>(batch, cnt);
    pool_kernel<<<NN / 64, 256, 0, stream>>>(h2, batch, pooled);
    // 9) head
    head_kernel<<<GG, 64, 0, stream>>>(pooled, cnt, Wc, bc, out);
}

// Round 2
// 303.303 us; speedup vs baseline: 1.0516x; 1.0516x over previous
//
#include <hip/hip_runtime.h>
#include <hip/hip_bf16.h>

#define NN 16384
#define EE 524288
#define DDIM 128
#define HDIM 256
#define CDIM 10
#define GG 64
#define MAXD 128
#define WPR 512   // bitmap words per row = NN/32

// workspace byte offsets (aliased; kernels are sequential on one stream)
#define OFF_BM   0ull          // 32 MB bitmap, dead after extract
#define OFF_Y1   0ull          // 8 MB   (alias BM)
#define OFF_H1   8388608ull    // 16 MB  (alias BM)
#define OFF_Y2   25165824ull   // 16 MB  (tail aliases BM, rest fresh)
#define OFF_ELL  41943040ull   // 8 MB
#define OFF_DIS  50331648ull   // 64 KB
#define OFF_DEG  50397184ull   // 64 KB
#define OFF_H2   0ull          // 16 MB  (alias Y1/H1, both dead by then)
#define OFF_POOL 50462720ull   // 64 KB
#define OFF_CNT  50528256ull   // 256 B

__global__ void zero_u4(uint4* p, int n16) {
    int i = blockIdx.x * blockDim.x + threadIdx.x;
    int stride = gridDim.x * blockDim.x;
    uint4 z = make_uint4(0u, 0u, 0u, 0u);
    for (; i < n16; i += stride) p[i] = z;
}

__global__ void zero_f(float* p, int n) {
    int i = blockIdx.x * blockDim.x + threadIdx.x;
    if (i < n) p[i] = 0.0f;
}

__global__ void selfloop_kernel(unsigned* bm) {
    int i = blockIdx.x * blockDim.x + threadIdx.x;
    if (i < NN) atomicOr(&bm[i * WPR + (i >> 5)], 1u << (i & 31));
}

__global__ void edge_kernel(const int* __restrict__ ei, unsigned* bm) {
    int e = blockIdx.x * blockDim.x + threadIdx.x;
    if (e < EE) {
        int s = ei[e];
        int d = ei[EE + e];
        atomicOr(&bm[s * WPR + (d >> 5)], 1u << (d & 31));
    }
}

// one wave per row: popcount + prefix scan -> ELL cols (sorted), deg, dis
__global__ void extract_kernel(const unsigned* __restrict__ bm,
                               int* __restrict__ ell, int* __restrict__ deg,
                               float* __restrict__ dis) {
    int gtid = blockIdx.x * blockDim.x + threadIdx.x;
    int row  = gtid >> 6;
    int lane = threadIdx.x & 63;
    if (row >= NN) return;
    const uint4* wp = (const uint4*)(bm + (size_t)row * WPR + lane * 8);
    uint4 a = wp[0];
    uint4 b = wp[1];
    unsigned w[8] = {a.x, a.y, a.z, a.w, b.x, b.y, b.z, b.w};
    int pc = 0;
#pragma unroll
    for (int k = 0; k < 8; k++) pc += __popc(w[k]);
    // inclusive scan
    int pre = pc;
#pragma unroll
    for (int off = 1; off < 64; off <<= 1) {
        int o = __shfl_up(pre, off, 64);
        if (lane >= off) pre += o;
    }
    int total = __shfl(pre, 63, 64);
    pre -= pc;  // exclusive
    int base = row * MAXD;
    int pos = pre;
#pragma unroll
    for (int k = 0; k < 8; k++) {
        unsigned bits = w[k];
        int cbase = lane * 256 + k * 32;
        while (bits) {
            int bit = __ffs(bits) - 1;
            if (pos < MAXD) ell[base + pos] = cbase + bit;
            pos++;
            bits &= bits - 1;
        }
    }
    if (lane == 0) {
        deg[row] = total < MAXD ? total : MAXD;
        dis[row] = 1.0f / sqrtf((float)total);
    }
}

// y[row,:] = dis[row] * sum_k dis[c_k] * x[c_k,:]
template <int DC>
__global__ void spmm_kernel(const float* __restrict__ x,
                            const int* __restrict__ ell,
                            const int* __restrict__ deg,
                            const float* __restrict__ dis,
                            float* __restrict__ y) {
    __shared__ int   sc[MAXD];
    __shared__ float sw[MAXD];
    int row = blockIdx.x;
    int t = threadIdx.x;
    int d = deg[row];
    if (t < d) {
        int c = ell[row * MAXD + t];
        sc[t] = c;
        sw[t] = dis[c];
    }
    __syncthreads();
    float acc = 0.0f;
    for (int k = 0; k < d; k++) acc = fmaf(sw[k], x[sc[k] * DC + t], acc);
    y[row * DC + t] = dis[row] * acc;
}

// H = relu(Y @ W + b); Y:[M,K] row-major, W:[K,256] row-major, H:[M,256].
// Block tile: 128 rows x 64 cols, 128 threads, 8x8 micro-tile.
// LDS: As[k][r] (transposed Y chunk), Bs[k][c]; k-chunk = 32.
template <int K>
__global__ __launch_bounds__(128) void gemm_relu_tile(
        const float* __restrict__ Y, const float* __restrict__ W,
        const float* __restrict__ bias, float* __restrict__ H) {
    __shared__ float As[32][132];  // [k][row], pad 132 (132%32==4)
    __shared__ float Bs[32][68];   // [k][col]
    const int r0 = blockIdx.x * 128;
    const int c0 = blockIdx.y * 64;
    const int t = threadIdx.x;
    const int tx = t & 7;    // col group: cols tx*8..+7
    const int ty = t >> 3;   // row group: rows ty*8..+7

    float acc[8][8];
#pragma unroll
    for (int i = 0; i < 8; i++)
#pragma unroll
        for (int j = 0; j < 8; j++) acc[i][j] = 0.0f;

    for (int d0 = 0; d0 < K; d0 += 32) {
        // --- stage A: Y[r0..+127][d0..+31] -> As[k][r] (transpose) ---
        // thread t owns row r0+t, loads 32 contiguous floats (8 float4)
        {
            const float* src = Y + (size_t)(r0 + t) * K + d0;
            float4 av[8];
#pragma unroll
            for (int q = 0; q < 8; q++) av[q] = ((const float4*)src)[q];
#pragma unroll
            for (int q = 0; q < 8; q++) {
                As[q * 4 + 0][t] = av[q].x;
                As[q * 4 + 1][t] = av[q].y;
                As[q * 4 + 2][t] = av[q].z;
                As[q * 4 + 3][t] = av[q].w;
            }
        }
        // --- stage B: W[d0..+31][c0..+63] -> Bs[k][c] ---
        // thread t: k = t>>2, 16 contiguous cols starting (t&3)*16
        {
            int bk = t >> 2;
            int bc = (t & 3) * 16;
            const float* wsrc = W + (size_t)(d0 + bk) * 256 + c0 + bc;
#pragma unroll
            for (int q = 0; q < 4; q++) {
                float4 wv = ((const float4*)wsrc)[q];
                *(float4*)&Bs[bk][bc + q * 4] = wv;
            }
        }
        __syncthreads();
#pragma unroll
        for (int k = 0; k < 32; k++) {
            float a[8], b[8];
            *(float4*)&a[0] = *(const float4*)&As[k][ty * 8];
            *(float4*)&a[4] = *(const float4*)&As[k][ty * 8 + 4];
            *(float4*)&b[0] = *(const float4*)&Bs[k][tx * 8];
            *(float4*)&b[4] = *(const float4*)&Bs[k][tx * 8 + 4];
#pragma unroll
            for (int i = 0; i < 8; i++)
#pragma unroll
                for (int j = 0; j < 8; j++)
                    acc[i][j] = fmaf(a[i], b[j], acc[i][j]);
        }
        __syncthreads();
    }

    // epilogue: bias + relu + store
    float bv[8];
#pragma unroll
    for (int j = 0; j < 8; j++) bv[j] = bias[c0 + tx * 8 + j];
#pragma unroll
    for (int i = 0; i < 8; i++) {
        float4 o0, o1;
        o0.x = fmaxf(acc[i][0] + bv[0], 0.0f);
        o0.y = fmaxf(acc[i][1] + bv[1], 0.0f);
        o0.z = fmaxf(acc[i][2] + bv[2], 0.0f);
        o0.w = fmaxf(acc[i][3] + bv[3], 0.0f);
        o1.x = fmaxf(acc[i][4] + bv[4], 0.0f);
        o1.y = fmaxf(acc[i][5] + bv[5], 0.0f);
        o1.z = fmaxf(acc[i][6] + bv[6], 0.0f);
        o1.w = fmaxf(acc[i][7] + bv[7], 0.0f);
        float* dst = H + (size_t)(r0 + ty * 8 + i) * 256 + c0 + tx * 8;
        ((float4*)dst)[0] = o0;
        ((float4*)dst)[1] = o1;
    }
}

// counts per graph (batch sorted, but histogram works regardless)
__global__ void count_kernel(const int* __restrict__ batch, float* cnt) {
    __shared__ int h[GG];
    int t = threadIdx.x;
    if (t < GG) h[t] = 0;
    __syncthreads();
    int i = blockIdx.x * blockDim.x + t;
    if (i < NN) atomicAdd(&h[batch[i]], 1);
    __syncthreads();
    if (t < GG && h[t] > 0) atomicAdd(&cnt[t], (float)h[t]);
}

// segment-sum 64 nodes per block (batch sorted -> run-length accumulate)
__global__ void pool_kernel(const float* __restrict__ h2,
                            const int* __restrict__ batch,
                            float* __restrict__ pooled) {
    int b = blockIdx.x;
    int t = threadIdx.x;  // feature dim, 256
    int n0 = b * 64;
    int cur = batch[n0];
    float acc = 0.0f;
    for (int n = 0; n < 64; n++) {
        int node = n0 + n;
        int g = batch[node];
        if (g != cur) {
            atomicAdd(&pooled[cur * 256 + t], acc);
            acc = 0.0f;
            cur = g;
        }
        acc += h2[node * 256 + t];
    }
    atomicAdd(&pooled[cur * 256 + t], acc);
}

// out[g,c] = (pooled[g,:]/cnt[g]) . Wc[:,c] + bc[c]
__global__ void head_kernel(const float* __restrict__ pooled,
                            const float* __restrict__ cnt,
                            const float* __restrict__ Wc,
                            const float* __restrict__ bc,
                            float* __restrict__ out) {
    int g = blockIdx.x;
    int l = threadIdx.x;  // 64
    float inv = 1.0f / fmaxf(cnt[g], 1.0f);
    float acc[CDIM];
#pragma unroll
    for (int c = 0; c < CDIM; c++) acc[c] = 0.0f;
    for (int t = l; t < 256; t += 64) {
        float pv = pooled[g * 256 + t] * inv;
#pragma unroll
        for (int c = 0; c < CDIM; c++) acc[c] = fmaf(pv, Wc[t * CDIM + c], acc[c]);
    }
#pragma unroll
    for (int c = 0; c < CDIM; c++) {
        float v = acc[c];
        for (int off = 32; off > 0; off >>= 1) v += __shfl_down(v, off, 64);
        if (l == 0) out[g * CDIM + c] = v + bc[c];
    }
}

extern "C" void kernel_launch(void* const* d_in, const int* in_sizes, int n_in,
                              void* d_out, int out_size, void* d_ws, size_t ws_size,
                              hipStream_t stream) {
    const float* x  = (const float*)d_in[0];
    const int*   ei = (const int*)d_in[1];
    const int*   batch = (const int*)d_in[2];
    const float* W1 = (const float*)d_in[3];
    const float* b1 = (const float*)d_in[4];
    const float* W2 = (const float*)d_in[5];
    const float* b2 = (const float*)d_in[6];
    const float* Wc = (const float*)d_in[7];
    const float* bc = (const float*)d_in[8];
    float* out = (float*)d_out;

    char* ws = (char*)d_ws;
    unsigned* bm  = (unsigned*)(ws + OFF_BM);
    float* y1     = (float*)(ws + OFF_Y1);
    float* h1     = (float*)(ws + OFF_H1);
    float* y2     = (float*)(ws + OFF_Y2);
    int*   ell    = (int*)(ws + OFF_ELL);
    float* dis    = (float*)(ws + OFF_DIS);
    int*   deg    = (int*)(ws + OFF_DEG);
    float* h2     = (float*)(ws + OFF_H2);
    float* pooled = (float*)(ws + OFF_POOL);
    float* cnt    = (float*)(ws + OFF_CNT);

    // 1) zero 32MB bitmap
    zero_u4<<<2048, 256, 0, stream>>>((uint4*)bm, (NN * WPR * 4) / 16);
    // 2) self loops + edges
    selfloop_kernel<<<NN / 256, 256, 0, stream>>>(bm);
    edge_kernel<<<EE / 256, 256, 0, stream>>>(ei, bm);
    // 3) bitmap -> ELL + deg + dis (wave per row)
    extract_kernel<<<(NN * 64) / 256, 256, 0, stream>>>(bm, ell, deg, dis);
    // 4) SpMM1: y1 = Ahat @ x   [N,128]
    spmm_kernel<DDIM><<<NN, DDIM, 0, stream>>>(x, ell, deg, dis, y1);
    // 5) GEMM1: h1 = relu(y1 @ W1 + b1)  [N,256]
    {
        dim3 grid(NN / 128, 256 / 64);
        gemm_relu_tile<DDIM><<<grid, 128, 0, stream>>>(y1, W1, b1, h1);
    }
    // 6) SpMM2: y2 = Ahat @ h1  [N,256]
    spmm_kernel<HDIM><<<NN, HDIM, 0, stream>>>(h1, ell, deg, dis, y2);
    // 7) GEMM2: h2 = relu(y2 @ W2 + b2) [N,256]
    {
        dim3 grid(NN / 128, 256 / 64);
        gemm_relu_tile<HDIM><<<grid, 128, 0, stream>>>(y2, W2, b2, h2);
    }
    // 8) pooled mean
    zero_f<<<(GG * 256 + GG + 255) / 256, 256, 0, stream>>>(pooled, GG * 256 + GG);
    count_kernel<<<NN / 256, 256, 0, stream>>>(batch, cnt);
    pool_kernel<<<NN / 64, 256, 0, stream>>>(h2, batch, pooled);
    // 9) head
    head_kernel<<<GG, 64, 0, stream>>>(pooled, cnt, Wc, bc, out);
}